// Round 1
// baseline (68.157 us; speedup 1.0000x reference)
//
#include <hip/hip_runtime.h>
#include <hip/hip_bf16.h>

typedef __bf16 bf16x8 __attribute__((ext_vector_type(8)));
typedef float f32x4 __attribute__((ext_vector_type(4)));
typedef unsigned short ushort4v __attribute__((ext_vector_type(4)));
typedef unsigned short ushort8v __attribute__((ext_vector_type(8)));

#define B_  16
#define C_  256
#define HW_ 4096
#define E_  8

__device__ inline unsigned short f2bf(float f) {
    unsigned int b = __builtin_bit_cast(unsigned int, f);
    b += 0x7FFFu + ((b >> 16) & 1u);   // round-to-nearest-even (inputs are finite)
    return (unsigned short)(b >> 16);
}

// ---------------- K1: pooled[b][c] = mean_{h,w} inputs[b,c,h,w] ----------------
__global__ __launch_bounds__(256) void k_pool(const float* __restrict__ in,
                                              float* __restrict__ pooled) {
    int bc = blockIdx.x;                       // 0..B*C-1
    const float* p = in + (size_t)bc * HW_;
    int t = threadIdx.x;
    float s = 0.f;
#pragma unroll
    for (int i = 0; i < 4; i++) {
        float4 v = *reinterpret_cast<const float4*>(p + (size_t)(t + i * 256) * 4);
        s += v.x + v.y + v.z + v.w;
    }
#pragma unroll
    for (int off = 32; off; off >>= 1) s += __shfl_down(s, off, 64);
    __shared__ float part[4];
    if ((t & 63) == 0) part[t >> 6] = s;
    __syncthreads();
    if (t == 0) {
        pooled[bc] = (part[0] + part[1] + part[2] + part[3]) * (1.0f / HW_);
    }
}

// ---------------- K2: router (logits -> softmax -> top2 gates) + eff bias ------
__global__ __launch_bounds__(256) void k_router(const float* __restrict__ pooled,
                                                const float* __restrict__ Wr,
                                                const float* __restrict__ br,
                                                const float* __restrict__ bexp,
                                                float* __restrict__ gates,
                                                float* __restrict__ biasE) {
    __shared__ float lg[B_][E_];
    __shared__ float gs[B_][E_];
    int t = threadIdx.x;
    if (t < B_ * E_) {
        int b = t >> 3, e = t & 7;
        float s = br[e];
        for (int c = 0; c < C_; c++) s += pooled[b * C_ + c] * Wr[c * E_ + e];
        lg[b][e] = s;
    }
    __syncthreads();
    if (t < B_) {
        float w[E_];
        float m = lg[t][0];
#pragma unroll
        for (int e = 1; e < E_; e++) m = fmaxf(m, lg[t][e]);
        float sum = 0.f;
#pragma unroll
        for (int e = 0; e < E_; e++) { w[e] = __expf(lg[t][e] - m); sum += w[e]; }
        float inv = 1.f / sum;
#pragma unroll
        for (int e = 0; e < E_; e++) w[e] *= inv;
        int i0 = 0;
#pragma unroll
        for (int e = 1; e < E_; e++) if (w[e] > w[i0]) i0 = e;
        int i1 = -1;
#pragma unroll
        for (int e = 0; e < E_; e++) {
            if (e == i0) continue;
            if (i1 < 0 || w[e] > w[i1]) i1 = e;
        }
#pragma unroll
        for (int e = 0; e < E_; e++) {
            float g = (e == i0 || e == i1) ? w[e] : 0.f;
            gs[t][e] = g;
            gates[t * E_ + e] = g;
        }
    }
    __syncthreads();
    // effective bias: biasE[b][d] = sum_e g[b,e] * b_exp[e,d]
    int d = t;
    for (int b = 0; b < B_; b++) {
        float s = 0.f;
#pragma unroll
        for (int e = 0; e < E_; e++) s += gs[b][e] * bexp[e * C_ + d];
        biasE[b * C_ + d] = s;
    }
}

// ---------------- K3: W_eff[b][d][c] = sum_e g[b,e] * W_exp[e,d,c]  (bf16) -----
__global__ __launch_bounds__(256) void k_weff(const float* __restrict__ Wexp,
                                              const float* __restrict__ gates,
                                              unsigned short* __restrict__ Weff) {
    int b = blockIdx.y;      // 16
    int dblk = blockIdx.x;   // 32 blocks of 8 d-rows
    __shared__ float g[E_];
    int t = threadIdx.x;
    if (t < E_) g[t] = gates[b * E_ + t];
    __syncthreads();
    int dloc = t >> 5, cq = t & 31;
    int d = dblk * 8 + dloc;
#pragma unroll
    for (int half = 0; half < 2; half++) {
        int c = (cq + half * 32) * 4;
        float4 acc = {0.f, 0.f, 0.f, 0.f};
#pragma unroll
        for (int e = 0; e < E_; e++) {
            float ge = g[e];                    // block-uniform -> no divergence
            if (ge != 0.f) {
                float4 w = *reinterpret_cast<const float4*>(
                    Wexp + ((size_t)(e * C_ + d)) * C_ + c);
                acc.x += ge * w.x; acc.y += ge * w.y;
                acc.z += ge * w.z; acc.w += ge * w.w;
            }
        }
        ushort4v o = { f2bf(acc.x), f2bf(acc.y), f2bf(acc.z), f2bf(acc.w) };
        *reinterpret_cast<ushort4v*>(Weff + ((size_t)(b * C_ + d)) * C_ + c) = o;
    }
}

// ---------------- K4: out[b] = x[b] + W_eff[b] @ x[b] + biasE[b] ---------------
// Per-batch GEMM: M=256 (d), N=4096 (p), K=256 (c). Tile 128x128, BK=32.
// 4 waves (2x2), each wave 64x64 = 4x4 fragments of 16x16x32 bf16 MFMA.
#define BK  32
#define LDA 40   // padded A row stride in shorts (80B, 16B-multiple)
#define LDB 36   // padded B row stride in shorts (72B, 8B-multiple)

__global__ __launch_bounds__(256) void k_gemm(const float* __restrict__ in,
                                              const unsigned short* __restrict__ Weff,
                                              const float* __restrict__ biasE,
                                              float* __restrict__ out) {
    __shared__ unsigned short As[128 * LDA];   // [row d][k] bf16
    __shared__ unsigned short Bs[128 * LDB];   // [row p][k] bf16 (transposed X)
    int t = threadIdx.x;
    int n0 = blockIdx.x * 128, m0 = blockIdx.y * 128, b = blockIdx.z;
    const float* inB = in + (size_t)b * C_ * HW_;
    const unsigned short* Wb = Weff + (size_t)b * C_ * C_;
    int lane = t & 63, wid = t >> 6;
    int wr = wid >> 1, wc = wid & 1;
    int kg = lane >> 4, lr = lane & 15;

    f32x4 acc[4][4];
#pragma unroll
    for (int i = 0; i < 4; i++)
#pragma unroll
        for (int j = 0; j < 4; j++) acc[i][j] = (f32x4){0.f, 0.f, 0.f, 0.f};

    for (int k0 = 0; k0 < C_; k0 += BK) {
        // ---- stage A: Weff[m0..m0+127][k0..k0+31] -> As (vector copy) ----
#pragma unroll
        for (int i = 0; i < 2; i++) {
            int chunk = t + i * 256;           // 512 chunks of 8 shorts
            int row = chunk >> 2, c8 = chunk & 3;
            ushort8v v = *reinterpret_cast<const ushort8v*>(
                Wb + (size_t)(m0 + row) * C_ + k0 + c8 * 8);
            *reinterpret_cast<ushort8v*>(&As[row * LDA + c8 * 8]) = v;
        }
        // ---- stage B: X[k0..k0+31][n0..n0+127] -> Bs transposed (fp32->bf16) ----
        {
            int p = t & 127, ch = t >> 7;
            const float* src = inB + (size_t)k0 * HW_ + n0 + p;
#pragma unroll
            for (int cq = 0; cq < 4; cq++) {
                int c = ch * 16 + cq * 4;
                float x0 = src[(size_t)(c + 0) * HW_];
                float x1 = src[(size_t)(c + 1) * HW_];
                float x2 = src[(size_t)(c + 2) * HW_];
                float x3 = src[(size_t)(c + 3) * HW_];
                ushort4v v = { f2bf(x0), f2bf(x1), f2bf(x2), f2bf(x3) };
                *reinterpret_cast<ushort4v*>(&Bs[p * LDB + c]) = v;
            }
        }
        __syncthreads();

        // ---- fragments + MFMA ----
        bf16x8 af[4], bfr[4];
#pragma unroll
        for (int mi = 0; mi < 4; mi++) {
            int row = wr * 64 + mi * 16 + lr;
            af[mi] = __builtin_bit_cast(bf16x8,
                *reinterpret_cast<const ushort8v*>(&As[row * LDA + kg * 8]));
        }
#pragma unroll
        for (int ni = 0; ni < 4; ni++) {
            int rowp = wc * 64 + ni * 16 + lr;
            ushort4v lo = *reinterpret_cast<const ushort4v*>(&Bs[rowp * LDB + kg * 8]);
            ushort4v hi = *reinterpret_cast<const ushort4v*>(&Bs[rowp * LDB + kg * 8 + 4]);
            ushort8v u = __builtin_shufflevector(lo, hi, 0, 1, 2, 3, 4, 5, 6, 7);
            bfr[ni] = __builtin_bit_cast(bf16x8, u);
        }
#pragma unroll
        for (int mi = 0; mi < 4; mi++)
#pragma unroll
            for (int ni = 0; ni < 4; ni++)
                acc[mi][ni] = __builtin_amdgcn_mfma_f32_16x16x32_bf16(
                    af[mi], bfr[ni], acc[mi][ni], 0, 0, 0);
        __syncthreads();
    }

    // ---- epilogue: += identity + bias, store fp32 ----
    float* outB = out + (size_t)b * C_ * HW_;
#pragma unroll
    for (int mi = 0; mi < 4; mi++) {
#pragma unroll
        for (int j = 0; j < 4; j++) {
            int row = m0 + wr * 64 + mi * 16 + kg * 4 + j;   // C/D: row=(lane>>4)*4+reg
            float bias = biasE[b * C_ + row];
            const float* inRow = inB + (size_t)row * HW_;
            float* outRow = outB + (size_t)row * HW_;
#pragma unroll
            for (int ni = 0; ni < 4; ni++) {
                int col = n0 + wc * 64 + ni * 16 + lr;        // C/D: col=lane&15
                outRow[col] = acc[mi][ni][j] + inRow[col] + bias;
            }
        }
    }
}

extern "C" void kernel_launch(void* const* d_in, const int* in_sizes, int n_in,
                              void* d_out, int out_size, void* d_ws, size_t ws_size,
                              hipStream_t stream) {
    const float* in   = (const float*)d_in[0];
    const float* Wr   = (const float*)d_in[1];
    const float* br   = (const float*)d_in[2];
    const float* Wexp = (const float*)d_in[3];
    const float* bexp = (const float*)d_in[4];
    // d_in[5] is k (==NUM_SUB==2, reference hardcodes top-2) -> ignored
    float* out = (float*)d_out;

    char* ws = (char*)d_ws;
    float* pooled         = (float*)(ws);                // 16 KB
    float* gates          = (float*)(ws + 16 * 1024);    // 512 B
    float* biasE          = (float*)(ws + 20 * 1024);    // 16 KB
    unsigned short* Weff  = (unsigned short*)(ws + 64 * 1024); // 2 MB bf16

    hipLaunchKernelGGL(k_pool,   dim3(B_ * C_), dim3(256), 0, stream, in, pooled);
    hipLaunchKernelGGL(k_router, dim3(1),       dim3(256), 0, stream,
                       pooled, Wr, br, bexp, gates, biasE);
    hipLaunchKernelGGL(k_weff,   dim3(32, B_),  dim3(256), 0, stream, Wexp, gates, Weff);
    hipLaunchKernelGGL(k_gemm,   dim3(HW_ / 128, C_ / 128, B_), dim3(256), 0, stream,
                       in, Weff, biasE, out);
}